// Round 2
// baseline (220.787 us; speedup 1.0000x reference)
//
#include <hip/hip_runtime.h>

// Problem constants
#define B_    16
#define A_    3
#define C_    80
#define H_    52
#define W_    52
#define T_    50
#define PLANE (H_*W_)                 // 2704
#define BSTRIDE (A_*(5+C_)*PLANE)     // 689520 floats per batch image
#define NLOCF 129792.0f               // B*H*W*A
#define NQ    (PLANE/4)               // 676 float4 groups per plane
#define NCH   (A_*81)                 // 243 channels per image we stream (f=4..84)
#define TOTU  (B_*NCH*NQ)             // 2,627,568 float4 groups
#define NBA   1024                    // blocks in streaming kernel
#define CLIPV 16.1180957f             // -log(1e-7)
#define BCE00 1.1920929e-07f          // -log(1 - 1e-7) in f32 (= BCE(clip(0), 0))

__device__ __forceinline__ float sigf(float x){ return 1.0f/(1.0f+__expf(-x)); }
__device__ __forceinline__ float clipp(float p){ return fminf(fmaxf(p, 1e-7f), 1.0f-1e-7f); }
// -log(1 - clip(sigmoid(v))) == min(softplus(v), -log(1e-7)); low-clip branch
// differs by <1e-7 per element and only for v < -16.1 (absent in N(0,1) data).
__device__ __forceinline__ float softp(float v){ return fminf(__logf(1.0f+__expf(v)), CLIPV); }

// Pure streaming reduce over conf+class channels (f=4..84 per anchor).
// No target dependence: assumes obj=0 / noobj=1 everywhere; corrections later.
__global__ __launch_bounds__(256) void stream_reduce(const float* __restrict__ pred,
                                                     float* __restrict__ partial){
    float accC = 0.0f;   // sum softp over conf channel (f==4)
    float accK = 0.0f;   // sum softp over class channels (f>=5)
    for (unsigned u = blockIdx.x*256u + threadIdx.x; u < TOTU; u += NBA*256u){
        unsigned q  = u % NQ;
        unsigned t  = u / NQ;            // b*NCH + p
        unsigned p  = t % NCH;
        unsigned b  = t / NCH;
        unsigned a  = p / 81u;
        unsigned fr = p - a*81u;         // 0 => conf, else class
        unsigned c  = a*85u + 4u + fr;   // channel in (B,255,H,W)
        const float4 v4 = *(const float4*)(pred + b*BSTRIDE + c*PLANE + q*4u);
        float s = softp(v4.x) + softp(v4.y) + softp(v4.z) + softp(v4.w);
        if (fr == 0u) accC += s; else accK += s;
    }
    #pragma unroll
    for (int off=32; off; off>>=1){
        accC += __shfl_down(accC, off, 64);
        accK += __shfl_down(accK, off, 64);
    }
    __shared__ float l[4][2];
    int lane = threadIdx.x & 63, wv = threadIdx.x >> 6;
    if (lane == 0){ l[wv][0] = accC; l[wv][1] = accK; }
    __syncthreads();
    if (threadIdx.x == 0){
        partial[blockIdx.x]       = l[0][0]+l[1][0]+l[2][0]+l[3][0];
        partial[NBA + blockIdx.x] = l[0][1]+l[1][1]+l[2][1]+l[3][1];
    }
}

// Single block: build targets, dedup, apply corrections at <=800 obj locations
// and <=2400 iou>thr conf locations, reduce stream partials, finalize.
__global__ __launch_bounds__(1024) void corrections_finalize(
        const float* __restrict__ tgt, const float* __restrict__ pred,
        const float* __restrict__ partial, float* __restrict__ out){
    __shared__ int s_loc[832], s_cell[832], s_mask[832];
    const float AW[3]={14.5f,19.5f,46.625f};   // ANCHORS / 8
    const float AH[3]={11.25f,24.75f,40.75f};
    int i = threadIdx.x;
    bool valid=false; int loc=-1, cell=-1, best=0, b=0, gi=0, gj=0, mask=0;
    float txv=0.f, tyv=0.f, twv=0.f, thv=0.f;
    if (i < B_*T_){
        b = i / T_;
        const float* r = tgt + i*5;
        if (r[0]+r[1]+r[2]+r[3]+r[4] > 0.0f){
            valid = true;
            float gx=r[1]*(float)W_, gy=r[2]*(float)H_;
            float gw=r[3]*(float)W_, gh=r[4]*(float)H_;
            gi=(int)gx; gj=(int)gy;
            float best_iou=-1.0f;
            #pragma unroll
            for (int a=0;a<3;a++){
                float inter = fminf(gw, AW[a]) * fminf(gh, AH[a]);
                float iou = inter / (gw*gh + AW[a]*AH[a] - inter + 1e-16f);
                if (iou > best_iou){ best_iou=iou; best=a; }
                if (iou > 0.5f) mask |= (1<<a);
            }
            cell = (b*H_ + gi)*W_ + gj;     // gi (from x) indexes H — reference quirk
            loc  = cell*A_ + best;
            txv = gx-(float)gi; tyv = gy-(float)gj;
            twv = logf(gw/AW[best] + 1e-16f);
            thv = logf(gh/AH[best] + 1e-16f);
        }
    }
    if (i < 832){ s_loc[i]=valid?loc:-1; s_cell[i]=valid?cell:-1; s_mask[i]=valid?mask:0; }
    __syncthreads();

    // acc: 0:x 1:y 2:w 3:h 4:conf_obj 5:conf_noobj(neg) 6:cls(neg) 7:npos 8:nmark
    //      9:S_conf 10:S_cls
    float acc[11];
    #pragma unroll
    for (int k=0;k<11;k++) acc[k]=0.0f;

    if (valid){
        // winner = highest flat (b,t) index with this loc (numpy last-write-wins)
        bool winner = true;
        for (int j=i+1; j<B_*T_; j++) if (s_loc[j]==loc){ winner=false; break; }
        if (winner){
            const float* base = pred + b*BSTRIDE + best*85*PLANE + gi*W_ + gj;
            float px=base[0], py=base[PLANE], pw=base[2*PLANE],
                  ph=base[3*PLANE], pc=base[4*PLANE];
            float p = clipp(sigf(px));
            acc[0] += -(txv*__logf(p) + (1.0f-txv)*__logf(1.0f-p)) - BCE00;
            p = clipp(sigf(py));
            acc[1] += -(tyv*__logf(p) + (1.0f-tyv)*__logf(1.0f-p)) - BCE00;
            float dw=pw-twv; acc[2]+=dw*dw;
            float dh=ph-thv; acc[3]+=dh*dh;
            p = clipp(sigf(pc));
            acc[4] += -__logf(p) - BCE00;
            acc[7] += 1.0f;
            // class channels at obj locs are excluded (m0==0): remove from S_cls
            #pragma unroll 16
            for (int f=0; f<C_; f++)
                acc[6] -= softp(base[(5+f)*PLANE]);
        }
        // canonical (lowest-index) thread per distinct cell handles noobj marks
        bool canon = true;
        for (int j=0; j<i; j++) if (s_cell[j]==cell){ canon=false; break; }
        if (canon){
            int mu = 0;
            for (int j=i; j<B_*T_; j++) if (s_cell[j]==cell) mu |= s_mask[j];
            if (mu){
                int rem = cell - b*PLANE;   // gi*W + gj
                #pragma unroll
                for (int a=0;a<3;a++) if ((mu>>a)&1){
                    float v = pred[b*BSTRIDE + (a*85+4)*PLANE + rem];
                    acc[5] -= softp(v);
                    acc[8] += 1.0f;
                }
            }
        }
    }

    // fold in stream partials (blockDim == NBA == 1024)
    acc[9]  = partial[i];
    acc[10] = partial[NBA + i];

    #pragma unroll
    for (int k=0;k<11;k++)
        for (int off=32; off; off>>=1)
            acc[k] += __shfl_down(acc[k], off, 64);
    __shared__ float red[16][11];
    int lane = i & 63, wv = i >> 6;
    if (lane == 0){
        #pragma unroll
        for (int k=0;k<11;k++) red[wv][k]=acc[k];
    }
    __syncthreads();
    if (i == 0){
        float c[11];
        #pragma unroll
        for (int k=0;k<11;k++){
            float s=0.0f;
            for (int w=0;w<16;w++) s += red[w][k];
            c[k]=s;
        }
        const float Nf = NLOCF;
        float lx    = BCE00 + c[0]/Nf;
        float ly    = BCE00 + c[1]/Nf;
        float lw    = c[2]/Nf;
        float lh    = c[3]/Nf;
        float lconf = (BCE00 + c[4]/Nf) + 0.5f*(c[9] + c[5] + c[8]*BCE00)/Nf;
        float lcls  = (c[10] + c[6]) / ((Nf - c[7])*(float)C_);
        float loss  = 2.5f*(lx+ly+lw+lh) + lconf + lcls;
        out[0]=loss; out[1]=lx; out[2]=ly; out[3]=lw; out[4]=lh; out[5]=lconf; out[6]=lcls;
    }
}

extern "C" void kernel_launch(void* const* d_in, const int* in_sizes, int n_in,
                              void* d_out, int out_size, void* d_ws, size_t ws_size,
                              hipStream_t stream) {
    const float* pred = (const float*)d_in[0];   // (16,255,52,52) f32
    const float* tgt  = (const float*)d_in[1];   // (16,50,5) f32
    float* partial = (float*)d_ws;               // 2*NBA floats, fully overwritten

    stream_reduce<<<NBA, 256, 0, stream>>>(pred, partial);
    corrections_finalize<<<1, 1024, 0, stream>>>(tgt, pred, partial, (float*)d_out);
}

// Round 3
// 137.808 us; speedup vs baseline: 1.6021x; 1.6021x over previous
//
#include <hip/hip_runtime.h>

// Problem constants
#define B_    16
#define A_    3
#define C_    80
#define H_    52
#define W_    52
#define T_    50
#define PLANE (H_*W_)                 // 2704
#define BSTRIDE (A_*(5+C_)*PLANE)     // 689520 floats per batch image
#define NLOC  (B_*H_*W_*A_)           // 129792
#define NLOCF 129792.0f
#define NQ    (PLANE/4)               // 676 float4 groups per plane
#define NCH   (A_*81)                 // 243 channels per image we stream (f=4..84)
#define TOTU  (B_*NCH*NQ)             // 2,627,568 float4 groups
#define NBA   1024                    // blocks in streaming kernel
#define NMARKW ((NLOC+31)/32)         // 4056 words of noobj-mark bits
#define NZERO (NLOC + NMARKW)         // words to zero (win + mark)
#define CLIPV 16.1180957f             // -log(1e-7)
#define BCE00 1.1920929e-07f          // -log(1 - 1e-7) in f32 (= BCE(clip(0), 0))

__device__ __forceinline__ float sigf(float x){ return 1.0f/(1.0f+__expf(-x)); }
__device__ __forceinline__ float clipp(float p){ return fminf(fmaxf(p, 1e-7f), 1.0f-1e-7f); }
// -log(1 - clip(sigmoid(v))) == min(softplus(v), -log(1e-7)); low-clip branch
// differs by <1e-7 per element and only for v < -16.1 (absent in N(0,1) data).
__device__ __forceinline__ float softp(float v){ return fminf(__logf(1.0f+__expf(v)), CLIPV); }

// Pure streaming reduce over conf+class channels (f=4..84 per anchor).
// Also zeroes the win[]/mark[] dedup arrays for the corrections kernel
// (stream-ordered: corrections launches after this kernel completes).
__global__ __launch_bounds__(256) void stream_reduce(const float* __restrict__ pred,
                                                     float* __restrict__ partial,
                                                     int* __restrict__ winmark){
    for (unsigned k = blockIdx.x*256u + threadIdx.x; k < NZERO; k += NBA*256u)
        winmark[k] = 0;

    float accC = 0.0f;   // sum softp over conf channel (f==4)
    float accK = 0.0f;   // sum softp over class channels (f>=5)
    for (unsigned u = blockIdx.x*256u + threadIdx.x; u < TOTU; u += NBA*256u){
        unsigned q  = u % NQ;
        unsigned t  = u / NQ;            // b*NCH + p
        unsigned p  = t % NCH;
        unsigned b  = t / NCH;
        unsigned a  = p / 81u;
        unsigned fr = p - a*81u;         // 0 => conf, else class
        unsigned c  = a*85u + 4u + fr;   // channel in (B,255,H,W)
        const float4 v4 = *(const float4*)(pred + b*BSTRIDE + c*PLANE + q*4u);
        float s = softp(v4.x) + softp(v4.y) + softp(v4.z) + softp(v4.w);
        if (fr == 0u) accC += s; else accK += s;
    }
    #pragma unroll
    for (int off=32; off; off>>=1){
        accC += __shfl_down(accC, off, 64);
        accK += __shfl_down(accK, off, 64);
    }
    __shared__ float l[4][2];
    int lane = threadIdx.x & 63, wv = threadIdx.x >> 6;
    if (lane == 0){ l[wv][0] = accC; l[wv][1] = accK; }
    __syncthreads();
    if (threadIdx.x == 0){
        partial[blockIdx.x]       = l[0][0]+l[1][0]+l[2][0]+l[3][0];
        partial[NBA + blockIdx.x] = l[0][1]+l[1][1]+l[2][1]+l[3][1];
    }
}

// Single block. O(n) dedup via global atomics:
//  - last-write-wins winner per loc: atomicMax(win[loc], i+1), re-check after sync
//  - unique (cell,a) noobj marks: atomicOr bitmask, old value identifies the setter
__global__ __launch_bounds__(1024) void corrections_finalize(
        const float* __restrict__ tgt, const float* __restrict__ pred,
        const float* __restrict__ partial, int* __restrict__ win,
        unsigned int* __restrict__ mark, float* __restrict__ out){
    const float AW[3]={14.5f,19.5f,46.625f};   // ANCHORS / 8
    const float AH[3]={11.25f,24.75f,40.75f};
    int i = threadIdx.x;

    // acc: 0:x 1:y 2:w 3:h 4:conf_obj 5:conf_noobj(neg) 6:cls(neg) 7:npos 8:nmark
    //      9:S_conf 10:S_cls
    float acc[11];
    #pragma unroll
    for (int k=0;k<11;k++) acc[k]=0.0f;

    bool valid=false; int loc=-1, best=0, b=0, gi=0, gj=0;
    float txv=0.f, tyv=0.f, twv=0.f, thv=0.f;
    if (i < B_*T_){
        b = i / T_;
        const float* r = tgt + i*5;
        if (r[0]+r[1]+r[2]+r[3]+r[4] > 0.0f){
            valid = true;
            float gx=r[1]*(float)W_, gy=r[2]*(float)H_;
            float gw=r[3]*(float)W_, gh=r[4]*(float)H_;
            gi=(int)gx; gj=(int)gy;
            float best_iou=-1.0f; int mask=0;
            #pragma unroll
            for (int a=0;a<3;a++){
                float inter = fminf(gw, AW[a]) * fminf(gh, AH[a]);
                float iou = inter / (gw*gh + AW[a]*AH[a] - inter + 1e-16f);
                if (iou > best_iou){ best_iou=iou; best=a; }
                if (iou > 0.5f) mask |= (1<<a);
            }
            int cell = (b*H_ + gi)*W_ + gj;  // gi (from x) indexes H — reference quirk
            loc  = cell*A_ + best;
            txv = gx-(float)gi; tyv = gy-(float)gj;
            twv = logf(gw/AW[best] + 1e-16f);
            thv = logf(gh/AH[best] + 1e-16f);

            atomicMax(&win[loc], i+1);       // last-write-wins by flat (b,t) index

            // noobj marks: dedup via bitmask; unique setter applies correction now
            #pragma unroll
            for (int a=0;a<3;a++) if ((mask>>a)&1){
                int p = cell*A_ + a;
                unsigned bit = 1u << (p & 31);
                unsigned old = atomicOr(&mark[p >> 5], bit);
                if (!(old & bit)){
                    float v = pred[b*BSTRIDE + (a*85+4)*PLANE + (cell - b*PLANE)];
                    acc[5] -= softp(v);
                    acc[8] += 1.0f;
                }
            }
        }
    }
    __syncthreads();   // all atomicMax done (block-wide order; atomics serialize at L2)

    if (valid && atomicMax(&win[loc], 0) == i+1){   // atomic read: L2-coherent
        const float* base = pred + b*BSTRIDE + best*85*PLANE + gi*W_ + gj;
        float px=base[0], py=base[PLANE], pw=base[2*PLANE],
              ph=base[3*PLANE], pc=base[4*PLANE];
        float p = clipp(sigf(px));
        acc[0] += -(txv*__logf(p) + (1.0f-txv)*__logf(1.0f-p)) - BCE00;
        p = clipp(sigf(py));
        acc[1] += -(tyv*__logf(p) + (1.0f-tyv)*__logf(1.0f-p)) - BCE00;
        float dw=pw-twv; acc[2]+=dw*dw;
        float dh=ph-thv; acc[3]+=dh*dh;
        p = clipp(sigf(pc));
        acc[4] += -__logf(p) - BCE00;
        acc[7] += 1.0f;
        // class channels at obj locs are excluded (m0==0): remove from S_cls
        #pragma unroll 16
        for (int f=0; f<C_; f++)
            acc[6] -= softp(base[(5+f)*PLANE]);
    }

    // fold in stream partials (blockDim == NBA == 1024)
    acc[9]  = partial[i];
    acc[10] = partial[NBA + i];

    #pragma unroll
    for (int k=0;k<11;k++)
        for (int off=32; off; off>>=1)
            acc[k] += __shfl_down(acc[k], off, 64);
    __shared__ float red[16][11];
    int lane = i & 63, wv = i >> 6;
    if (lane == 0){
        #pragma unroll
        for (int k=0;k<11;k++) red[wv][k]=acc[k];
    }
    __syncthreads();
    if (i == 0){
        float c[11];
        #pragma unroll
        for (int k=0;k<11;k++){
            float s=0.0f;
            for (int w=0;w<16;w++) s += red[w][k];
            c[k]=s;
        }
        const float Nf = NLOCF;
        float lx    = BCE00 + c[0]/Nf;
        float ly    = BCE00 + c[1]/Nf;
        float lw    = c[2]/Nf;
        float lh    = c[3]/Nf;
        float lconf = (BCE00 + c[4]/Nf) + 0.5f*(c[9] + c[5] + c[8]*BCE00)/Nf;
        float lcls  = (c[10] + c[6]) / ((Nf - c[7])*(float)C_);
        float loss  = 2.5f*(lx+ly+lw+lh) + lconf + lcls;
        out[0]=loss; out[1]=lx; out[2]=ly; out[3]=lw; out[4]=lh; out[5]=lconf; out[6]=lcls;
    }
}

extern "C" void kernel_launch(void* const* d_in, const int* in_sizes, int n_in,
                              void* d_out, int out_size, void* d_ws, size_t ws_size,
                              hipStream_t stream) {
    const float* pred = (const float*)d_in[0];   // (16,255,52,52) f32
    const float* tgt  = (const float*)d_in[1];   // (16,50,5) f32

    float* partial = (float*)d_ws;               // 2*NBA floats
    int*   winmark = (int*)(partial + 2*NBA);    // NLOC win + NMARKW mark words
    int*   win     = winmark;
    unsigned int* mark = (unsigned int*)(winmark + NLOC);

    stream_reduce<<<NBA, 256, 0, stream>>>(pred, partial, winmark);
    corrections_finalize<<<1, 1024, 0, stream>>>(tgt, pred, partial, win, mark,
                                                 (float*)d_out);
}

// Round 4
// 95.367 us; speedup vs baseline: 2.3151x; 1.4450x over previous
//
#include <hip/hip_runtime.h>

// Problem constants
#define B_    16
#define A_    3
#define C_    80
#define H_    52
#define W_    52
#define T_    50
#define PLANE (H_*W_)                 // 2704
#define BSTRIDE (A_*(5+C_)*PLANE)     // 689520 floats per batch image
#define NLOCF 129792.0f               // B*H*W*A
#define NQ    (PLANE/4)               // 676 float4 groups per plane
#define NCH   (A_*81)                 // 243 channels per image we stream (f=4..84)
#define TOTU  (B_*NCH*NQ)             // 2,627,568 float4 groups
#define NBA   1024                    // blocks in stream_apply
#define NTHR  256
#define GRIDT (NBA*NTHR)
#define MAXW  (B_*T_)                 // 800 max winners
#define MAXM  (B_*T_*A_)              // 2400 max marks
#define NCOMP 11
#define CLIPV 16.1180957f             // -log(1e-7)
#define BCE00 1.1920929e-07f          // -log(1 - 1e-7) in f32 (= BCE(clip(0), 0))
// acc: 0:x 1:y 2:w 3:h 4:conf_obj 5:conf_noobj(neg) 6:cls(neg) 7:npos 8:nmark
//      9:S_conf 10:S_cls

__device__ __forceinline__ float sigf(float x){ return 1.0f/(1.0f+__expf(-x)); }
__device__ __forceinline__ float clipp(float p){ return fminf(fmaxf(p, 1e-7f), 1.0f-1e-7f); }
// -log(1 - clip(sigmoid(v))) == min(softplus(v), -log(1e-7)); low-clip branch
// differs by <1e-7 per element and only for v < -16.1 (absent in N(0,1) data).
__device__ __forceinline__ float softp(float v){ return fminf(__logf(1.0f+__expf(v)), CLIPV); }

// 1 block. All dedup in LDS hash tables (no global zero-init, no pred reads).
// Emits compact correction records for the parallel apply pass.
__global__ __launch_bounds__(1024) void build_targets(
        const float* __restrict__ tgt,
        int* __restrict__ cnt,            // [0]=nwin [1]=nmark
        int* __restrict__ win_off,        // <=800 base offsets into pred
        float* __restrict__ win_t,        // <=800 x {tx,ty,tw,th}
        int* __restrict__ mark_off){      // <=2400 conf-element offsets into pred
    __shared__ int hkey[2048], hval[2048];   // winner table: loc -> max flat idx+1
    __shared__ int mkey[4096];               // mark set: loc(cell,a) membership
    __shared__ int c_win, c_mark;
    const float AW[3]={14.5f,19.5f,46.625f};   // ANCHORS / 8
    const float AH[3]={11.25f,24.75f,40.75f};
    int i = threadIdx.x;
    { // init tables
        hkey[i] = -1; hkey[i+1024] = -1;
        hval[i] = 0;  hval[i+1024] = 0;
        mkey[i] = -1; mkey[i+1024] = -1; mkey[i+2048] = -1; mkey[i+3072] = -1;
        if (i == 0){ c_win = 0; c_mark = 0; }
    }
    __syncthreads();

    bool valid=false; int loc=-1, slot=-1, b=0, best=0, gi=0, gj=0;
    float txv=0.f, tyv=0.f, twv=0.f, thv=0.f;
    if (i < B_*T_){
        b = i / T_;
        const float* r = tgt + i*5;
        if (r[0]+r[1]+r[2]+r[3]+r[4] > 0.0f){
            valid = true;
            float gx=r[1]*(float)W_, gy=r[2]*(float)H_;
            float gw=r[3]*(float)W_, gh=r[4]*(float)H_;
            gi=(int)gx; gj=(int)gy;
            float best_iou=-1.0f; int mask=0;
            #pragma unroll
            for (int a=0;a<3;a++){
                float inter = fminf(gw, AW[a]) * fminf(gh, AH[a]);
                float iou = inter / (gw*gh + AW[a]*AH[a] - inter + 1e-16f);
                if (iou > best_iou){ best_iou=iou; best=a; }
                if (iou > 0.5f) mask |= (1<<a);
            }
            int cell = (b*H_ + gi)*W_ + gj;  // gi (from x) indexes H — reference quirk
            loc = cell*A_ + best;
            txv = gx-(float)gi; tyv = gy-(float)gj;
            twv = logf(gw/AW[best] + 1e-16f);
            thv = logf(gh/AH[best] + 1e-16f);

            // winner table insert (last-write-wins by flat (b,t) index)
            int s = (int)(((unsigned)loc * 2654435761u) >> 21) & 2047;
            for (;;){
                int old = atomicCAS(&hkey[s], -1, loc);
                if (old == -1 || old == loc){ atomicMax(&hval[s], i+1); slot = s; break; }
                s = (s+1) & 2047;
            }
            // noobj marks: unique (cell,a) setter emits a record
            #pragma unroll
            for (int a=0;a<3;a++) if ((mask>>a)&1){
                int key = cell*A_ + a;
                int m = (int)(((unsigned)key * 2654435761u) >> 20) & 4095;
                for (;;){
                    int old = atomicCAS(&mkey[m], -1, key);
                    if (old == -1){
                        int idx = atomicAdd(&c_mark, 1);
                        mark_off[idx] = b*BSTRIDE + (a*85+4)*PLANE + (cell - b*PLANE);
                        break;
                    }
                    if (old == key) break;    // duplicate
                    m = (m+1) & 4095;
                }
            }
        }
    }
    __syncthreads();
    if (valid && hval[slot] == i+1){          // this thread is the winner for loc
        int idx = atomicAdd(&c_win, 1);
        win_off[idx] = b*BSTRIDE + best*85*PLANE + gi*W_ + gj;
        win_t[idx*4+0]=txv; win_t[idx*4+1]=tyv; win_t[idx*4+2]=twv; win_t[idx*4+3]=thv;
    }
    __syncthreads();
    if (i == 0){ cnt[0] = c_win; cnt[1] = c_mark; }
}

// Grid-wide: coalesced streaming reduce over conf+class channels (obj=0/noobj=1
// baseline) + grid-stride correction items (<=67200 scattered loads, fully
// parallel). 11 partials per block.
__global__ __launch_bounds__(NTHR) void stream_apply(
        const float* __restrict__ pred, const int* __restrict__ cnt,
        const int* __restrict__ win_off, const float* __restrict__ win_t,
        const int* __restrict__ mark_off, float* __restrict__ partial){
    float acc[NCOMP];
    #pragma unroll
    for (int k=0;k<NCOMP;k++) acc[k]=0.0f;

    const unsigned gid = blockIdx.x*NTHR + threadIdx.x;

    // ---- correction items ----
    const int ncw = cnt[0], ncm = cnt[1];
    const int nitems = ncw*81 + ncm;
    for (int j = (int)gid; j < nitems; j += GRIDT){
        if (j < ncw*81){
            int w = j / 81, k = j - w*81;
            const float* base = pred + win_off[w];
            if (k == 0){
                float px=base[0], py=base[PLANE], pw=base[2*PLANE],
                      ph=base[3*PLANE], pc=base[4*PLANE];
                float tx=win_t[w*4+0], ty=win_t[w*4+1],
                      tw=win_t[w*4+2], th=win_t[w*4+3];
                float p = clipp(sigf(px));
                acc[0] += -(tx*__logf(p) + (1.0f-tx)*__logf(1.0f-p)) - BCE00;
                p = clipp(sigf(py));
                acc[1] += -(ty*__logf(p) + (1.0f-ty)*__logf(1.0f-p)) - BCE00;
                float dw=pw-tw; acc[2]+=dw*dw;
                float dh=ph-th; acc[3]+=dh*dh;
                p = clipp(sigf(pc));
                acc[4] += -__logf(p) - BCE00;
                acc[7] += 1.0f;
            } else {
                // class channel 4+k at an obj loc is excluded (m0==0): remove
                acc[6] -= softp(base[(4+k)*PLANE]);
            }
        } else {
            acc[5] -= softp(pred[mark_off[j - ncw*81]]);
            acc[8] += 1.0f;
        }
    }

    // ---- streaming reduce ----
    for (unsigned u = gid; u < TOTU; u += GRIDT){
        unsigned q  = u % NQ;
        unsigned t  = u / NQ;            // b*NCH + p
        unsigned p  = t % NCH;
        unsigned b  = t / NCH;
        unsigned a  = p / 81u;
        unsigned fr = p - a*81u;         // 0 => conf, else class
        unsigned c  = a*85u + 4u + fr;   // channel in (B,255,H,W)
        const float4 v4 = *(const float4*)(pred + b*BSTRIDE + c*PLANE + q*4u);
        float s = softp(v4.x) + softp(v4.y) + softp(v4.z) + softp(v4.w);
        if (fr == 0u) acc[9] += s; else acc[10] += s;
    }

    // ---- block reduce ----
    #pragma unroll
    for (int k=0;k<NCOMP;k++)
        for (int off=32; off; off>>=1)
            acc[k] += __shfl_down(acc[k], off, 64);
    __shared__ float l[4][NCOMP];
    int lane = threadIdx.x & 63, wv = threadIdx.x >> 6;
    if (lane == 0){
        #pragma unroll
        for (int k=0;k<NCOMP;k++) l[wv][k] = acc[k];
    }
    __syncthreads();
    if (threadIdx.x < NCOMP){
        int k = threadIdx.x;
        partial[k*NBA + blockIdx.x] = l[0][k]+l[1][k]+l[2][k]+l[3][k];
    }
}

__global__ __launch_bounds__(1024) void finalize(const float* __restrict__ partial,
                                                 float* __restrict__ out){
    int i = threadIdx.x;
    float acc[NCOMP];
    #pragma unroll
    for (int k=0;k<NCOMP;k++) acc[k] = partial[k*NBA + i];
    #pragma unroll
    for (int k=0;k<NCOMP;k++)
        for (int off=32; off; off>>=1)
            acc[k] += __shfl_down(acc[k], off, 64);
    __shared__ float red[16][NCOMP];
    int lane = i & 63, wv = i >> 6;
    if (lane == 0){
        #pragma unroll
        for (int k=0;k<NCOMP;k++) red[wv][k]=acc[k];
    }
    __syncthreads();
    if (i == 0){
        float c[NCOMP];
        #pragma unroll
        for (int k=0;k<NCOMP;k++){
            float s=0.0f;
            for (int w=0;w<16;w++) s += red[w][k];
            c[k]=s;
        }
        const float Nf = NLOCF;
        float lx    = BCE00 + c[0]/Nf;
        float ly    = BCE00 + c[1]/Nf;
        float lw    = c[2]/Nf;
        float lh    = c[3]/Nf;
        float lconf = (BCE00 + c[4]/Nf) + 0.5f*(c[9] + c[5] + c[8]*BCE00)/Nf;
        float lcls  = (c[10] + c[6]) / ((Nf - c[7])*(float)C_);
        float loss  = 2.5f*(lx+ly+lw+lh) + lconf + lcls;
        out[0]=loss; out[1]=lx; out[2]=ly; out[3]=lw; out[4]=lh; out[5]=lconf; out[6]=lcls;
    }
}

extern "C" void kernel_launch(void* const* d_in, const int* in_sizes, int n_in,
                              void* d_out, int out_size, void* d_ws, size_t ws_size,
                              hipStream_t stream) {
    const float* pred = (const float*)d_in[0];   // (16,255,52,52) f32
    const float* tgt  = (const float*)d_in[1];   // (16,50,5) f32

    int*   ip       = (int*)d_ws;
    int*   cnt      = ip;                        // 2
    int*   win_off  = ip + 2;                    // 800
    int*   mark_off = win_off + MAXW;            // 2400
    float* win_t    = (float*)(mark_off + MAXM); // 3200
    float* partial  = win_t + 4*MAXW;            // NCOMP*NBA — fully overwritten

    build_targets<<<1, 1024, 0, stream>>>(tgt, cnt, win_off, win_t, mark_off);
    stream_apply<<<NBA, NTHR, 0, stream>>>(pred, cnt, win_off, win_t, mark_off, partial);
    finalize<<<1, 1024, 0, stream>>>(partial, (float*)d_out);
}